// Round 1
// baseline (691.742 us; speedup 1.0000x reference)
//
#include <hip/hip_runtime.h>

// Problem constants (from reference)
#define NTOKENS    8192
#define TOPK       2
#define HIDDEN     4096
#define NUM_GROUPS 2
#define M_FULL     (NTOKENS * TOPK)   // 16384
#define H4         (HIDDEN / 4)       // 1024 float4 per row

// out[t,h] = sum_{g,k} buf[g, idx[t,k], h]
// One block per token. 256 threads, each handles H4/256 = 4 float4 columns.
__global__ __launch_bounds__(256) void topk_gather_rs_kernel(
    const float4* __restrict__ buf,   // (NUM_GROUPS, M_FULL, H4) as float4
    const int*    __restrict__ idx,   // (NTOKENS, TOPK)
    float4*       __restrict__ out)   // (NTOKENS, H4)
{
    const int t   = blockIdx.x;
    const int tid = threadIdx.x;

    const int r0 = idx[t * TOPK + 0];
    const int r1 = idx[t * TOPK + 1];

    const size_t g1off = (size_t)M_FULL * H4;   // group-1 base offset in float4 units

    const float4* __restrict__ p00 = buf + (size_t)r0 * H4;          // g0, k0
    const float4* __restrict__ p01 = buf + (size_t)r1 * H4;          // g0, k1
    const float4* __restrict__ p10 = buf + g1off + (size_t)r0 * H4;  // g1, k0
    const float4* __restrict__ p11 = buf + g1off + (size_t)r1 * H4;  // g1, k1

    float4* __restrict__ o = out + (size_t)t * H4;

#pragma unroll
    for (int j = 0; j < H4 / 256; ++j) {
        const int c = j * 256 + tid;
        const float4 a = p00[c];
        const float4 b = p01[c];
        const float4 cc = p10[c];
        const float4 d = p11[c];
        float4 s;
        s.x = (a.x + b.x) + (cc.x + d.x);
        s.y = (a.y + b.y) + (cc.y + d.y);
        s.z = (a.z + b.z) + (cc.z + d.z);
        s.w = (a.w + b.w) + (cc.w + d.w);
        o[c] = s;
    }
}

extern "C" void kernel_launch(void* const* d_in, const int* in_sizes, int n_in,
                              void* d_out, int out_size, void* d_ws, size_t ws_size,
                              hipStream_t stream) {
    const float4* buf = (const float4*)d_in[0];
    const int*    idx = (const int*)d_in[1];
    float4*       out = (float4*)d_out;

    topk_gather_rs_kernel<<<NTOKENS, 256, 0, stream>>>(buf, idx, out);
}